// Round 1
// baseline (520.761 us; speedup 1.0000x reference)
//
#include <hip/hip_runtime.h>

// Problem dims (fixed by the reference)
#define R_DIM 64
#define C_DIM 1024
#define B_DIM 2
#define E_DIM 256
#define Q_DIM 256
#define H_DIM 8
#define D_DIM 32
#define ROW_STRIDE ((size_t)C_DIM * B_DIM * E_DIM) /* 524288 floats between r rows */
#define LDS_STRIDE 264                             /* 256 + 8 bf16 pad -> 2-way-only LDS conflicts */
#define OUT_MAIN ((size_t)R_DIM * C_DIM * B_DIM * E_DIM) /* 33554432 */

typedef short bf16x8 __attribute__((ext_vector_type(8)));
typedef float f32x4 __attribute__((ext_vector_type(4)));

__device__ __forceinline__ unsigned short f2bf(float x) {
  // round-to-nearest-even fp32 -> bf16 (raw bits; inputs are finite/sane)
  unsigned int u = __builtin_bit_cast(unsigned int, x);
  u += 0x7FFFu + ((u >> 16) & 1u);
  return (unsigned short)(u >> 16);
}

// ---------------------------------------------------------------------------
// Kernel 1 (tiny, 1 block): q projection, folded score weights w[h,n,e] and
// bias terms bterm[h,n].
//   q[n,h,d]   = (query @ Wq.T + bq) * scaling          (scaling = 1/8)
//   w[h,n,e]   = sum_d q[n,h,d] * Wk[h*32+d, e]
//   bterm[h,n] = sum_d q[n,h,d] * bk[h*32+d]
// ---------------------------------------------------------------------------
__global__ void prep_qw(const float* __restrict__ query, const float* __restrict__ Wq,
                        const float* __restrict__ bq, const float* __restrict__ Wk,
                        const float* __restrict__ bk, float* __restrict__ w_out,
                        float* __restrict__ bterm_out) {
  __shared__ float q_sm[B_DIM * E_DIM];
  const int t = threadIdx.x;
  for (int idx = t; idx < B_DIM * E_DIM; idx += 256) {
    int n = idx / E_DIM, e = idx % E_DIM;
    float s = bq[e];
    for (int k = 0; k < Q_DIM; k++) s += query[n * Q_DIM + k] * Wq[e * Q_DIM + k];
    q_sm[idx] = s * 0.125f; // D^-0.5 / sqrt(B) = 1/(sqrt(32)*sqrt(2)) = 1/8
  }
  __syncthreads();
  for (int idx = t; idx < H_DIM * B_DIM * E_DIM; idx += 256) {
    int e2 = idx % E_DIM;
    int hn = idx / E_DIM;
    int n = hn % B_DIM, h = hn / B_DIM;
    float s = 0.f;
    for (int d = 0; d < D_DIM; d++)
      s += q_sm[n * E_DIM + h * D_DIM + d] * Wk[(h * D_DIM + d) * E_DIM + e2];
    w_out[idx] = s; // layout [h][n][e]
  }
  if (t < H_DIM * B_DIM) {
    int n = t % B_DIM, h = t / B_DIM;
    float s = 0.f;
    for (int d = 0; d < D_DIM; d++)
      s += q_sm[n * E_DIM + h * D_DIM + d] * bk[h * D_DIM + d];
    bterm_out[t] = s; // layout [h][n]
  }
}

// ---------------------------------------------------------------------------
// Kernel 2: pre-pack Wv and Wo (fp32) into bf16 MFMA B-fragment order so the
// main kernel's B loads are 16B/lane fully-coalesced.
// GEMM1: v[r,e] = sum_k val[r,k]*Wv[e,k]  -> B[k][n=e] = Wv[e][k]
// GEMM2: o[r,o] = sum_k vs[r,k]*Wo[o,k]   -> B[k][n=o] = Wo[o][k]
// Fragment: lane holds B[kstep*32 + (lane>>4)*8 + j][ntile*16 + (lane&15)], j=0..7
// Packed linear index: ((ntile*8 + kstep)*64 + lane)*8 + j
// ---------------------------------------------------------------------------
__global__ void prepack(const float* __restrict__ Wv, const float* __restrict__ Wo,
                        unsigned short* __restrict__ B1p, unsigned short* __restrict__ B2p) {
  int gidx = blockIdx.x * blockDim.x + threadIdx.x; // 0..16383
  const float* src = (gidx < 8192) ? Wv : Wo;
  unsigned short* dst = (gidx < 8192) ? B1p : B2p;
  int li = gidx & 8191;
  int lane = li & 63;
  int pk = li >> 6; // ntile*8 + kstep
  int ntile = pk >> 3, kstep = pk & 7;
  int row = ntile * 16 + (lane & 15);        // output-col index (e or o)
  int col0 = kstep * 32 + (lane >> 4) * 8;   // k index base
  for (int jj = 0; jj < 8; jj++)
    dst[li * 8 + jj] = f2bf(src[row * E_DIM + col0 + jj]);
}

// ---------------------------------------------------------------------------
// Kernel 3: block per (j,n). keysum[e] = sum_r key[r,j,n,e] (streaming 134MB),
// then scores[h,n,j] = sum_e keysum[e]*w[h,n,e] + R*bterm[h,n].
// ---------------------------------------------------------------------------
__global__ void scores_kernel(const float* __restrict__ key, const float* __restrict__ w,
                              const float* __restrict__ bterm, float* __restrict__ scores) {
  const int bid = blockIdx.x;
  const int j = bid >> 1, n = bid & 1;
  const int e = threadIdx.x; // 256 threads = 256 e values
  const float* kp = key + ((size_t)j * B_DIM + n) * E_DIM + e;
  float ks = 0.f;
#pragma unroll 8
  for (int r = 0; r < R_DIM; r++) ks += kp[(size_t)r * ROW_STRIDE];

  __shared__ float red[H_DIM][4];
  const int lane = e & 63, wv = e >> 6;
  for (int h = 0; h < H_DIM; h++) {
    float p = ks * w[(h * B_DIM + n) * E_DIM + e];
    for (int off = 32; off > 0; off >>= 1) p += __shfl_down(p, off, 64);
    if (lane == 0) red[h][wv] = p;
  }
  __syncthreads();
  if (e < H_DIM) {
    float s = red[e][0] + red[e][1] + red[e][2] + red[e][3] +
              (float)R_DIM * bterm[e * B_DIM + n];
    scores[(e * B_DIM + n) * C_DIM + j] = s;
  }
}

// ---------------------------------------------------------------------------
// Kernel 4: softmax over C per (h,n). Writes probs to ws AND to d_out tail.
// ---------------------------------------------------------------------------
__global__ void softmax_kernel(const float* __restrict__ scores, float* __restrict__ probs,
                               float* __restrict__ probs_out) {
  const int hn = blockIdx.x;
  const int t = threadIdx.x;
  const float* s = scores + (size_t)hn * C_DIM;
  float v[4];
  float mx = -1e30f;
  for (int i = 0; i < 4; i++) {
    v[i] = s[t + i * 256];
    mx = fmaxf(mx, v[i]);
  }
  __shared__ float sm[4];
  const int lane = t & 63, wv = t >> 6;
  for (int off = 32; off > 0; off >>= 1) mx = fmaxf(mx, __shfl_down(mx, off, 64));
  if (lane == 0) sm[wv] = mx;
  __syncthreads();
  mx = fmaxf(fmaxf(sm[0], sm[1]), fmaxf(sm[2], sm[3]));
  float sum = 0.f;
  for (int i = 0; i < 4; i++) {
    v[i] = expf(v[i] - mx);
    sum += v[i];
  }
  for (int off = 32; off > 0; off >>= 1) sum += __shfl_down(sum, off, 64);
  __syncthreads(); // protect sm reuse
  if (lane == 0) sm[wv] = sum;
  __syncthreads();
  sum = sm[0] + sm[1] + sm[2] + sm[3];
  float inv = 1.0f / sum;
  for (int i = 0; i < 4; i++) {
    float p = v[i] * inv;
    probs[(size_t)hn * C_DIM + t + i * 256] = p;
    probs_out[(size_t)hn * C_DIM + t + i * 256] = p;
  }
}

// ---------------------------------------------------------------------------
// Kernel 5: the big fused pass. Block per (j,n): stage 64 value rows as bf16
// in LDS, GEMM1 (@Wv.T, +bv), scale per-head by probs, LDS transpose,
// GEMM2 (@Wo.T, +bo), write out. MFMA 16x16x32 bf16; wave w owns rows 16w..16w+15.
// ---------------------------------------------------------------------------
__global__ __launch_bounds__(256, 4) void fused_pv(
    const float* __restrict__ value, const unsigned short* __restrict__ B1p,
    const unsigned short* __restrict__ B2p, const float* __restrict__ bv,
    const float* __restrict__ bo, const float* __restrict__ probs,
    float* __restrict__ out) {
  __shared__ unsigned short tile[64 * LDS_STRIDE]; // 33.8 KB
  const int bid = blockIdx.x;
  const int j = bid >> 1, n = bid & 1;
  const int t = threadIdx.x;
  const int lane = t & 63;
  const int wv = t >> 6;
  const int l15 = lane & 15;
  const int quad = lane >> 4;

  // --- stage value[*, j, n, :] -> bf16 LDS (1 KB contiguous per wave-instr) ---
  const float* vbase = value + ((size_t)j * B_DIM + n) * E_DIM;
  for (int row = wv; row < 64; row += 4) {
    const float4 v4 = *(((const float4*)(vbase + (size_t)row * ROW_STRIDE)) + lane);
    ushort4 u;
    u.x = f2bf(v4.x); u.y = f2bf(v4.y); u.z = f2bf(v4.z); u.w = f2bf(v4.w);
    *(ushort4*)(&tile[row * LDS_STRIDE + lane * 4]) = u;
  }
  __syncthreads();

  f32x4 acc[16];
  const f32x4 zero = {0.f, 0.f, 0.f, 0.f};
#pragma unroll
  for (int i = 0; i < 16; i++) acc[i] = zero;

  const int arow = (16 * wv + l15) * LDS_STRIDE + quad * 8;

  // --- GEMM1: v = val @ Wv.T ---
#pragma unroll
  for (int ks = 0; ks < 8; ks++) {
    bf16x8 a = *(const bf16x8*)(&tile[arow + ks * 32]);
#pragma unroll
    for (int nt = 0; nt < 16; nt++) {
      bf16x8 b = ((const bf16x8*)B1p)[(nt * 8 + ks) * 64 + lane];
      acc[nt] = __builtin_amdgcn_mfma_f32_16x16x32_bf16(a, b, acc[nt], 0, 0, 0);
    }
  }

  float pr[8];
#pragma unroll
  for (int h = 0; h < 8; h++) pr[h] = probs[((size_t)h * B_DIM + n) * C_DIM + j];

  __syncthreads(); // GEMM1 LDS reads complete before overwrite
  // --- epilogue1: +bv, *probs(head), bf16, transpose via LDS ---
#pragma unroll
  for (int nt = 0; nt < 16; nt++) {
    int e = nt * 16 + l15;
    float bias = bv[e];
    float p = pr[e >> 5];
#pragma unroll
    for (int i = 0; i < 4; i++) {
      int m = 16 * wv + quad * 4 + i;
      tile[m * LDS_STRIDE + e] = f2bf((acc[nt][i] + bias) * p);
    }
    acc[nt] = zero;
  }
  __syncthreads();

  // --- GEMM2: out = vs @ Wo.T ---
#pragma unroll
  for (int ks = 0; ks < 8; ks++) {
    bf16x8 a = *(const bf16x8*)(&tile[arow + ks * 32]);
#pragma unroll
    for (int nt = 0; nt < 16; nt++) {
      bf16x8 b = ((const bf16x8*)B2p)[(nt * 8 + ks) * 64 + lane];
      acc[nt] = __builtin_amdgcn_mfma_f32_16x16x32_bf16(a, b, acc[nt], 0, 0, 0);
    }
  }

  // --- epilogue2: +bo, store fp32 ---
  float* obase = out + ((size_t)j * B_DIM + n) * E_DIM;
#pragma unroll
  for (int nt = 0; nt < 16; nt++) {
    int o = nt * 16 + l15;
    float bias = bo[o];
#pragma unroll
    for (int i = 0; i < 4; i++) {
      int m = 16 * wv + quad * 4 + i;
      obase[(size_t)m * ROW_STRIDE + o] = acc[nt][i] + bias;
    }
  }
}

// ---------------------------------------------------------------------------
extern "C" void kernel_launch(void* const* d_in, const int* in_sizes, int n_in,
                              void* d_out, int out_size, void* d_ws, size_t ws_size,
                              hipStream_t stream) {
  const float* query = (const float*)d_in[0];
  const float* key   = (const float*)d_in[1];
  const float* value = (const float*)d_in[2];
  const float* Wq = (const float*)d_in[3];
  const float* bq = (const float*)d_in[4];
  const float* Wk = (const float*)d_in[5];
  const float* bk = (const float*)d_in[6];
  const float* Wv = (const float*)d_in[7];
  const float* bv = (const float*)d_in[8];
  const float* Wo = (const float*)d_in[9];
  const float* bo = (const float*)d_in[10];
  float* out = (float*)d_out;

  // workspace layout (floats): w[4096] | bterm[16] | scores[16384] | probs[16384]
  // then bf16: B1p (128 KB) | B2p (128 KB). Total ~410 KB.
  float* ws_f = (float*)d_ws;
  float* w_ = ws_f;
  float* bterm_ = ws_f + 4096;
  float* scores_ = ws_f + 4112;
  float* probs_ = ws_f + 20496;
  unsigned short* B1p = (unsigned short*)((char*)d_ws + 147520);
  unsigned short* B2p = (unsigned short*)((char*)d_ws + 147520 + 131072);

  prep_qw<<<dim3(1), dim3(256), 0, stream>>>(query, Wq, bq, Wk, bk, w_, bterm_);
  prepack<<<dim3(64), dim3(256), 0, stream>>>(Wv, Wo, B1p, B2p);
  scores_kernel<<<dim3(C_DIM * B_DIM), dim3(256), 0, stream>>>(key, w_, bterm_, scores_);
  softmax_kernel<<<dim3(H_DIM * B_DIM), dim3(256), 0, stream>>>(scores_, probs_,
                                                                out + OUT_MAIN);
  fused_pv<<<dim3(C_DIM * B_DIM), dim3(256), 0, stream>>>(value, B1p, B2p, bv, bo,
                                                          probs_, out);
}

// Round 2
// 402.439 us; speedup vs baseline: 1.2940x; 1.2940x over previous
//
#include <hip/hip_runtime.h>

// Problem dims (fixed by the reference)
#define R_DIM 64
#define C_DIM 1024
#define B_DIM 2
#define E_DIM 256
#define Q_DIM 256
#define H_DIM 8
#define D_DIM 32
#define ROW_STRIDE ((size_t)C_DIM * B_DIM * E_DIM) /* 524288 floats between r rows */
#define LDS_STRIDE 264                             /* bf16 tile stride (256+8 pad) */
#define OS 260                                     /* fp32 otile stride (256+4 pad) */
#define OUT_MAIN ((size_t)R_DIM * C_DIM * B_DIM * E_DIM) /* 33554432 */

typedef short bf16x8 __attribute__((ext_vector_type(8)));
typedef float f32x4 __attribute__((ext_vector_type(4)));

__device__ __forceinline__ unsigned short f2bf(float x) {
  unsigned int u = __builtin_bit_cast(unsigned int, x);
  u += 0x7FFFu + ((u >> 16) & 1u);
  return (unsigned short)(u >> 16);
}

// ---------------------------------------------------------------------------
// prep_q: q[n,e] = (query @ Wq.T + bq)*0.125   (2 blocks x 256 threads)
// ---------------------------------------------------------------------------
__global__ void prep_q(const float* __restrict__ query, const float* __restrict__ Wq,
                       const float* __restrict__ bq, float* __restrict__ q_out) {
  int idx = blockIdx.x * 256 + threadIdx.x; // 0..511
  int n = idx >> 8, e = idx & 255;
  const float4* qr = (const float4*)(query + (size_t)n * Q_DIM);
  const float4* wr = (const float4*)(Wq + (size_t)e * Q_DIM);
  float s = bq[e];
#pragma unroll 8
  for (int k = 0; k < Q_DIM / 4; k++) {
    float4 a = qr[k], b = wr[k];
    s += a.x * b.x + a.y * b.y + a.z * b.z + a.w * b.w;
  }
  q_out[idx] = s * 0.125f; // D^-0.5 / sqrt(B) = 1/8
}

// ---------------------------------------------------------------------------
// prep_w: w[h,n,e] = sum_d q[n,h*32+d]*Wk[h*32+d, e]; bterm[h*2+n] likewise w/ bk.
// 16 blocks x 256 threads; coalesced over e.
// ---------------------------------------------------------------------------
__global__ void prep_w(const float* __restrict__ q, const float* __restrict__ Wk,
                       const float* __restrict__ bk, float* __restrict__ w_out,
                       float* __restrict__ bterm_out) {
  int idx = blockIdx.x * 256 + threadIdx.x; // 0..4095  = ((h*2+n)*256 + e)
  int e2 = idx & 255;
  int hn = idx >> 8;
  int n = hn & 1, h = hn >> 1;
  float s = 0.f;
#pragma unroll
  for (int d = 0; d < D_DIM; d++)
    s += q[n * E_DIM + h * D_DIM + d] * Wk[(h * D_DIM + d) * E_DIM + e2];
  w_out[idx] = s;
  if (idx < H_DIM * B_DIM) {
    int nn = idx & 1, hh = idx >> 1;
    float sb = 0.f;
#pragma unroll
    for (int d = 0; d < D_DIM; d++)
      sb += q[nn * E_DIM + hh * D_DIM + d] * bk[hh * D_DIM + d];
    bterm_out[idx] = sb;
  }
}

// ---------------------------------------------------------------------------
// prepack: Wv/Wo fp32 -> bf16 MFMA B-fragment order.
// Packed linear index: ((ntile*8 + kstep)*64 + lane)*8 + j
// lane holds B[kstep*32+(lane>>4)*8+j][ntile*16+(lane&15)]
// ---------------------------------------------------------------------------
__global__ void prepack(const float* __restrict__ Wv, const float* __restrict__ Wo,
                        unsigned short* __restrict__ B1p, unsigned short* __restrict__ B2p) {
  int gidx = blockIdx.x * blockDim.x + threadIdx.x; // 0..16383
  const float* src = (gidx < 8192) ? Wv : Wo;
  unsigned short* dst = (gidx < 8192) ? B1p : B2p;
  int li = gidx & 8191;
  int lane = li & 63;
  int pk = li >> 6;
  int ntile = pk >> 3, kstep = pk & 7;
  int row = ntile * 16 + (lane & 15);
  int col0 = kstep * 32 + (lane >> 4) * 8;
  for (int jj = 0; jj < 8; jj++)
    dst[li * 8 + jj] = f2bf(src[row * E_DIM + col0 + jj]);
}

// ---------------------------------------------------------------------------
// scores: block per (j,n). keysum[e] = sum_r key[r,j,n,e], then
// scores[h,n,j] = sum_e keysum[e]*w[h,n,e] + R*bterm[h,n].
// ---------------------------------------------------------------------------
__global__ void scores_kernel(const float* __restrict__ key, const float* __restrict__ w,
                              const float* __restrict__ bterm, float* __restrict__ scores) {
  const int bid = blockIdx.x;
  const int j = bid >> 1, n = bid & 1;
  const int e = threadIdx.x;
  const float* kp = key + ((size_t)j * B_DIM + n) * E_DIM + e;
  float ks = 0.f;
#pragma unroll 8
  for (int r = 0; r < R_DIM; r++) ks += kp[(size_t)r * ROW_STRIDE];

  __shared__ float red[H_DIM][4];
  const int lane = e & 63, wv = e >> 6;
  for (int h = 0; h < H_DIM; h++) {
    float p = ks * w[(h * B_DIM + n) * E_DIM + e];
    for (int off = 32; off > 0; off >>= 1) p += __shfl_down(p, off, 64);
    if (lane == 0) red[h][wv] = p;
  }
  __syncthreads();
  if (e < H_DIM) {
    float s = red[e][0] + red[e][1] + red[e][2] + red[e][3] +
              (float)R_DIM * bterm[e * B_DIM + n];
    scores[(e * B_DIM + n) * C_DIM + j] = s;
  }
}

// ---------------------------------------------------------------------------
// softmax over C per (h,n). Writes probs to ws AND to d_out tail.
// ---------------------------------------------------------------------------
__global__ void softmax_kernel(const float* __restrict__ scores, float* __restrict__ probs,
                               float* __restrict__ probs_out) {
  const int hn = blockIdx.x;
  const int t = threadIdx.x;
  const float* s = scores + (size_t)hn * C_DIM;
  float v[4];
  float mx = -1e30f;
  for (int i = 0; i < 4; i++) {
    v[i] = s[t + i * 256];
    mx = fmaxf(mx, v[i]);
  }
  __shared__ float sm[4];
  const int lane = t & 63, wv = t >> 6;
  for (int off = 32; off > 0; off >>= 1) mx = fmaxf(mx, __shfl_down(mx, off, 64));
  if (lane == 0) sm[wv] = mx;
  __syncthreads();
  mx = fmaxf(fmaxf(sm[0], sm[1]), fmaxf(sm[2], sm[3]));
  float sum = 0.f;
  for (int i = 0; i < 4; i++) {
    v[i] = expf(v[i] - mx);
    sum += v[i];
  }
  for (int off = 32; off > 0; off >>= 1) sum += __shfl_down(sum, off, 64);
  __syncthreads();
  if (lane == 0) sm[wv] = sum;
  __syncthreads();
  sum = sm[0] + sm[1] + sm[2] + sm[3];
  float inv = 1.0f / sum;
  for (int i = 0; i < 4; i++) {
    float p = v[i] * inv;
    probs[(size_t)hn * C_DIM + t + i * 256] = p;
    probs_out[(size_t)hn * C_DIM + t + i * 256] = p;
  }
}

// ---------------------------------------------------------------------------
// fused_pv: block per (j,n). Wave wv owns ALL 64 rows x 64 cols [wv*64, wv*64+64).
// Per k-step: 4 A-frags (LDS, reused across 4 n-tiles) + 4 B-frags (L2, reused
// across 4 m-tiles) -> 16 MFMA. Output goes through an fp32 LDS half-tile
// (aliased with the dead bf16 tile) for 1KB-contiguous row stores.
// ---------------------------------------------------------------------------
union SmemT {
  unsigned short tile[64 * LDS_STRIDE]; // 33792 B  (staging + transpose, bf16)
  float otile[32 * OS];                 // 33280 B  (output half-tile, fp32)
};

__global__ __launch_bounds__(256, 4) void fused_pv(
    const float* __restrict__ value, const unsigned short* __restrict__ B1p,
    const unsigned short* __restrict__ B2p, const float* __restrict__ bv,
    const float* __restrict__ bo, const float* __restrict__ probs,
    float* __restrict__ out) {
  __shared__ SmemT sm;
  const int bid = blockIdx.x;
  const int j = bid >> 1, n = bid & 1;
  const int t = threadIdx.x;
  const int lane = t & 63;
  const int wv = t >> 6;
  const int l15 = lane & 15;
  const int quad = lane >> 4;

  // --- stage value[*, j, n, :] -> bf16 LDS ---
  const float* vbase = value + ((size_t)j * B_DIM + n) * E_DIM;
#pragma unroll
  for (int row = wv; row < 64; row += 4) {
    const float4 v4 = *(((const float4*)(vbase + (size_t)row * ROW_STRIDE)) + lane);
    ushort4 u;
    u.x = f2bf(v4.x); u.y = f2bf(v4.y); u.z = f2bf(v4.z); u.w = f2bf(v4.w);
    *(ushort4*)(&sm.tile[row * LDS_STRIDE + lane * 4]) = u;
  }
  __syncthreads();

  f32x4 acc[4][4]; // [m-tile][n-tile]
  const f32x4 zero = {0.f, 0.f, 0.f, 0.f};
#pragma unroll
  for (int mt = 0; mt < 4; mt++)
#pragma unroll
    for (int nt = 0; nt < 4; nt++) acc[mt][nt] = zero;

  // --- GEMM1: v = val @ Wv.T ---
#pragma unroll
  for (int ks = 0; ks < 8; ks++) {
    bf16x8 a[4], b[4];
#pragma unroll
    for (int mt = 0; mt < 4; mt++)
      a[mt] = *(const bf16x8*)(&sm.tile[(mt * 16 + l15) * LDS_STRIDE + ks * 32 + quad * 8]);
#pragma unroll
    for (int nt = 0; nt < 4; nt++)
      b[nt] = ((const bf16x8*)B1p)[((wv * 4 + nt) * 8 + ks) * 64 + lane];
#pragma unroll
    for (int mt = 0; mt < 4; mt++)
#pragma unroll
      for (int nt = 0; nt < 4; nt++)
        acc[mt][nt] = __builtin_amdgcn_mfma_f32_16x16x32_bf16(a[mt], b[nt], acc[mt][nt], 0, 0, 0);
  }

  // probs for this wave's two heads (cols wv*64 .. wv*64+63 -> heads 2wv, 2wv+1)
  const float p0 = probs[((size_t)(2 * wv) * B_DIM + n) * C_DIM + j];
  const float p1 = probs[((size_t)(2 * wv + 1) * B_DIM + n) * C_DIM + j];

  __syncthreads(); // all GEMM1 LDS reads done before overwrite
  // --- epilogue1: +bv, *probs(head), bf16, write back (in-place transpose src) ---
#pragma unroll
  for (int nt = 0; nt < 4; nt++) {
    const int e = wv * 64 + nt * 16 + l15;
    const float bias = bv[e];
    const float p = (nt < 2) ? p0 : p1;
#pragma unroll
    for (int mt = 0; mt < 4; mt++) {
#pragma unroll
      for (int i = 0; i < 4; i++) {
        int row = mt * 16 + quad * 4 + i;
        sm.tile[row * LDS_STRIDE + e] = f2bf((acc[mt][nt][i] + bias) * p);
      }
      acc[mt][nt] = zero;
    }
  }
  __syncthreads();

  // --- GEMM2: out = vs @ Wo.T ---
#pragma unroll
  for (int ks = 0; ks < 8; ks++) {
    bf16x8 a[4], b[4];
#pragma unroll
    for (int mt = 0; mt < 4; mt++)
      a[mt] = *(const bf16x8*)(&sm.tile[(mt * 16 + l15) * LDS_STRIDE + ks * 32 + quad * 8]);
#pragma unroll
    for (int nt = 0; nt < 4; nt++)
      b[nt] = ((const bf16x8*)B2p)[((wv * 4 + nt) * 8 + ks) * 64 + lane];
#pragma unroll
    for (int mt = 0; mt < 4; mt++)
#pragma unroll
      for (int nt = 0; nt < 4; nt++)
        acc[mt][nt] = __builtin_amdgcn_mfma_f32_16x16x32_bf16(a[mt], b[nt], acc[mt][nt], 0, 0, 0);
  }

  // --- epilogue2: +bo, fp32 LDS half-tile -> 1KB-contiguous row stores ---
  float* obase = out + ((size_t)j * B_DIM + n) * E_DIM;
#pragma unroll
  for (int h2 = 0; h2 < 2; h2++) {
    __syncthreads(); // GEMM2 tile reads (h2=0) / prior otile ds_reads (h2=1) done
#pragma unroll
    for (int mt = 2 * h2; mt < 2 * h2 + 2; mt++) {
#pragma unroll
      for (int nt = 0; nt < 4; nt++) {
        const int e = wv * 64 + nt * 16 + l15;
        const float bias = bo[e];
#pragma unroll
        for (int i = 0; i < 4; i++) {
          int lr = (mt - 2 * h2) * 16 + quad * 4 + i;
          sm.otile[lr * OS + e] = acc[mt][nt][i] + bias;
        }
      }
    }
    __syncthreads();
#pragma unroll
    for (int it = 0; it < 8; it++) {
      int idx = it * 256 + t;
      int lr = idx >> 6;   // 0..31
      int f4 = idx & 63;   // float4 index within row
      float4 v = *(const float4*)(&sm.otile[lr * OS + f4 * 4]);
      *(float4*)(&obase[(size_t)(h2 * 32 + lr) * ROW_STRIDE + f4 * 4]) = v;
    }
  }
}

// ---------------------------------------------------------------------------
extern "C" void kernel_launch(void* const* d_in, const int* in_sizes, int n_in,
                              void* d_out, int out_size, void* d_ws, size_t ws_size,
                              hipStream_t stream) {
  const float* query = (const float*)d_in[0];
  const float* key   = (const float*)d_in[1];
  const float* value = (const float*)d_in[2];
  const float* Wq = (const float*)d_in[3];
  const float* bq = (const float*)d_in[4];
  const float* Wk = (const float*)d_in[5];
  const float* bk = (const float*)d_in[6];
  const float* Wv = (const float*)d_in[7];
  const float* bv = (const float*)d_in[8];
  const float* Wo = (const float*)d_in[9];
  const float* bo = (const float*)d_in[10];
  float* out = (float*)d_out;

  // workspace (floats): w[4096] | bterm[16] | scores[16384] | probs[16384]
  // then bf16: B1p (128KB) | B2p (128KB).  q (512 floats) aliases scores.
  float* ws_f = (float*)d_ws;
  float* w_ = ws_f;
  float* bterm_ = ws_f + 4096;
  float* scores_ = ws_f + 4112;
  float* q_ = scores_; // alias: q dead before scores_kernel writes
  float* probs_ = ws_f + 20496;
  unsigned short* B1p = (unsigned short*)((char*)d_ws + 147520);
  unsigned short* B2p = (unsigned short*)((char*)d_ws + 147520 + 131072);

  prep_q<<<dim3(2), dim3(256), 0, stream>>>(query, Wq, bq, q_);
  prep_w<<<dim3(16), dim3(256), 0, stream>>>(q_, Wk, bk, w_, bterm_);
  prepack<<<dim3(64), dim3(256), 0, stream>>>(Wv, Wo, B1p, B2p);
  scores_kernel<<<dim3(C_DIM * B_DIM), dim3(256), 0, stream>>>(key, w_, bterm_, scores_);
  softmax_kernel<<<dim3(H_DIM * B_DIM), dim3(256), 0, stream>>>(scores_, probs_,
                                                                out + OUT_MAIN);
  fused_pv<<<dim3(C_DIM * B_DIM), dim3(256), 0, stream>>>(value, B1p, B2p, bv, bo,
                                                          probs_, out);
}